// Round 5
// baseline (250.371 us; speedup 1.0000x reference)
//
#include <hip/hip_runtime.h>
#include <math.h>

#define B_DIM 32
#define T_DIM 2048
#define D_DIM 512
#define V_DIM 5
#define L_DIM 256
#define LN2D 0.6931471805599453

typedef const float __attribute__((address_space(1)))* gas_fp;
typedef float __attribute__((address_space(3)))* las_fp;

// Kernel 1: logits = hs @ W + b, log_softmax over V, probs. Thread-per-row.
__global__ __launch_bounds__(256) void k_logits_softmax(
    const float* __restrict__ hs, const float* __restrict__ W,
    const float* __restrict__ bias, float* __restrict__ logp,
    float* __restrict__ probs)
{
    int r = blockIdx.x * blockDim.x + threadIdx.x;   // row in [0, B*T)
    const float* x = hs + (size_t)r * D_DIM;

    float acc[V_DIM];
#pragma unroll
    for (int v = 0; v < V_DIM; ++v) acc[v] = bias[v];

    for (int k = 0; k < D_DIM; k += 8) {
        float4 xa = *reinterpret_cast<const float4*>(x + k);
        float4 xb = *reinterpret_cast<const float4*>(x + k + 4);
        const float xs[8] = {xa.x, xa.y, xa.z, xa.w, xb.x, xb.y, xb.z, xb.w};
#pragma unroll
        for (int j = 0; j < 8; ++j) {
#pragma unroll
            for (int v = 0; v < V_DIM; ++v)
                acc[v] = fmaf(xs[j], W[(k + j) * V_DIM + v], acc[v]);
        }
    }

    float m = fmaxf(fmaxf(fmaxf(acc[0], acc[1]), fmaxf(acc[2], acc[3])), acc[4]);
    float e[V_DIM];
    float s = 0.f;
#pragma unroll
    for (int v = 0; v < V_DIM; ++v) { e[v] = __expf(acc[v] - m); s += e[v]; }
    float lse = m + __logf(s);
    float inv = 1.f / s;

    size_t base = (size_t)r * V_DIM;
#pragma unroll
    for (int v = 0; v < V_DIM; ++v) {
        logp[base + v]  = acc[v] - lse;
        probs[base + v] = e[v] * inv;
    }
}

// Kernel 2: CTC forward scan. Linear-prob domain in DOUBLE, single global
// frame, exact pow2 renorm every 16 steps (round-3-proven numerics: f64
// holds the ~400-bit within-slice spread + <=160-bit drift; f32 per-lane
// BFP (round 4) left a 32-nat loss error at 96.6% of threshold).
// Structure from round 4: one wave/sample, 8 states/lane (+1 ghost) in
// registers, probs staged once to LDS via global_load_lds, per-lane ds_read
// pointers (symbol select baked into addresses), fma-encoded skips,
// register prefetch one 4-step block ahead, one f64 shfl per step.
__global__ __launch_bounds__(64) void k_ctc(
    const float* __restrict__ probs, const int* __restrict__ ys_pad,
    const int* __restrict__ hlens, const int* __restrict__ ys_lens,
    float* __restrict__ nll_out)
{
    __shared__ float  s_probs[(T_DIM + 8) * V_DIM];   // +8 rows: prefetch pad
    __shared__ double s_alpha[513];

    const int b    = blockIdx.x;
    const int lane = threadIdx.x;        // 0..63
    const int hlen = hlens[b];
    const int lb   = ys_lens[b];
    const int Sb   = 2 * lb + 1;
    const float* pb = probs + (size_t)b * T_DIM * V_DIM;
    const int*  yrow = ys_pad + b * L_DIM;

    // ---- stage all T*V probs for this sample into LDS (40 KB) ----
    for (int i = 0; i < (T_DIM * V_DIM) / 64; ++i) {
        __builtin_amdgcn_global_load_lds((gas_fp)(pb + i * 64 + lane),
                                         (las_fp)(&s_probs[i * 64]), 4, 0, 0);
    }
    asm volatile("s_waitcnt vmcnt(0)" ::: "memory");

    // labels for this lane's 4 odd states (8l+{1,3,5,7} -> labels 4l..4l+3)
    const int y0 = yrow[4 * lane + 0];
    const int y1 = yrow[4 * lane + 1];
    const int y2 = yrow[4 * lane + 2];
    const int y3 = yrow[4 * lane + 3];
    const int ym1 = (lane > 0) ? yrow[4 * lane - 1] : -1;

    // skip flags as 0/1 doubles (labels never blank per setup)
    const double sk0 = ((lane > 0) && (y0 != ym1)) ? 1.0 : 0.0;
    const double sk1 = (y1 != y0) ? 1.0 : 0.0;
    const double sk2 = (y2 != y1) ? 1.0 : 0.0;
    const double sk3 = (y3 != y2) ? 1.0 : 0.0;

    // valid-state masks; invalid states zeroed at every renorm
    bool vmask[9];
#pragma unroll
    for (int i = 0; i < 9; ++i) vmask[i] = (8 * lane + i) < Sb;

    double aA[9], aB[9];
#pragma unroll
    for (int i = 0; i < 9; ++i) aA[i] = 0.0;
    if (lane == 0) {
        aA[0] = (double)s_probs[0];      // state 0: blank at t=0
        aA[1] = (double)s_probs[y0];     // state 1: first label at t=0
    }
    int E = 0;   // global (wave-uniform) base-2 exponent, exact

    // per-lane LDS read pointers, advanced +20 dwords per 4-step block
    const float* p_bl = s_probs + V_DIM;          // blank col, row t=1
    const float* p_y0 = s_probs + V_DIM + y0;
    const float* p_y1 = s_probs + V_DIM + y1;
    const float* p_y2 = s_probs + V_DIM + y2;
    const float* p_y3 = s_probs + V_DIM + y3;

#define LOADQ(dst)                                                        \
    {                                                                     \
        _Pragma("unroll")                                                 \
        for (int s_ = 0; s_ < 4; ++s_) {                                  \
            dst[s_ * 5 + 0] = (double)p_bl[s_ * 5];                       \
            dst[s_ * 5 + 1] = (double)p_y0[s_ * 5];                       \
            dst[s_ * 5 + 2] = (double)p_y1[s_ * 5];                       \
            dst[s_ * 5 + 3] = (double)p_y2[s_ * 5];                       \
            dst[s_ * 5 + 4] = (double)p_y3[s_ * 5];                       \
        }                                                                 \
        p_bl += 20; p_y0 += 20; p_y1 += 20; p_y2 += 20; p_y3 += 20;       \
    }

#define STEPX(O, N, L, s_)                                                \
    {                                                                     \
        double p7 = __shfl_up(O[7], 1, 64);                               \
        if (lane == 0) p7 = 0.0;                                          \
        const double bl_ = L[(s_) * 5 + 0];                               \
        N[0] = (O[0] + p7) * bl_;                                         \
        N[1] = fma(sk0, p7,   O[1] + O[0]) * L[(s_) * 5 + 1];             \
        N[2] = (O[2] + O[1]) * bl_;                                       \
        N[3] = fma(sk1, O[1], O[3] + O[2]) * L[(s_) * 5 + 2];             \
        N[4] = (O[4] + O[3]) * bl_;                                       \
        N[5] = fma(sk2, O[3], O[5] + O[4]) * L[(s_) * 5 + 3];             \
        N[6] = (O[6] + O[5]) * bl_;                                       \
        N[7] = fma(sk3, O[5], O[7] + O[6]) * L[(s_) * 5 + 4];             \
        N[8] = (O[8] + O[7]) * bl_;                                       \
    }

#define STEP4(L)                                                          \
    STEPX(aA, aB, L, 0); STEPX(aB, aA, L, 1);                             \
    STEPX(aA, aB, L, 2); STEPX(aB, aA, L, 3);

// Global renorm (wave-uniform E): exact pow2, invalid states zeroed.
#define RENORM()                                                          \
    {                                                                     \
        double m_ = 0.0;                                                  \
        _Pragma("unroll")                                                 \
        for (int i_ = 0; i_ < 9; ++i_)                                    \
            m_ = fmax(m_, vmask[i_] ? aA[i_] : 0.0);                      \
        m_ = fmax(m_, __shfl_xor(m_, 1, 64));                             \
        m_ = fmax(m_, __shfl_xor(m_, 2, 64));                             \
        m_ = fmax(m_, __shfl_xor(m_, 4, 64));                             \
        m_ = fmax(m_, __shfl_xor(m_, 8, 64));                             \
        m_ = fmax(m_, __shfl_xor(m_, 16, 64));                            \
        m_ = fmax(m_, __shfl_xor(m_, 32, 64));                            \
        int e_ = 0;                                                       \
        (void)frexp(m_, &e_);            /* e_=0 when m_=0 */             \
        double sc_ = ldexp(1.0, -e_);                                     \
        _Pragma("unroll")                                                 \
        for (int i_ = 0; i_ < 9; ++i_)                                    \
            aA[i_] = vmask[i_] ? aA[i_] * sc_ : 0.0;                      \
        E += e_;                                                          \
    }

    const int NS = hlen - 1;       // steps t = 1..NS
    const int nfull = NS >> 2;     // full 4-step blocks
    double lpA[20], lpB[20];
    LOADQ(lpA);                    // rows 1..4

    int blk = 0;
    for (; blk + 2 <= nfull; blk += 2) {
        LOADQ(lpB);                // prefetch next block
        STEP4(lpA);
        LOADQ(lpA);                // prefetch block after
        STEP4(lpB);
        if (blk & 2) RENORM();     // every 16 steps (f64 headroom: ~560 of
                                   // 1022 bits worst-case -> safe)
    }
    if (blk < nfull) {             // one leftover full block, data in lpA
        STEP4(lpA);
    }
    // tail steps (0..3): t = 4*nfull+1 .. NS
    for (int tt = 4 * nfull + 1; tt <= NS; ++tt) {
        const float* r_ = s_probs + tt * V_DIM;
        double lt[5] = { (double)r_[0], (double)r_[y0], (double)r_[y1],
                         (double)r_[y2], (double)r_[y3] };
        STEPX(aA, aB, lt, 0);
#pragma unroll
        for (int i = 0; i < 9; ++i) aA[i] = aB[i];
    }

    // ---- readout (single global frame: plain add) ----
#pragma unroll
    for (int i = 0; i < 8; ++i) s_alpha[8 * lane + i] = aA[i];
    if (lane == 63) s_alpha[512] = aA[8];
    __syncthreads();
    if (lane == 0) {
        int i1 = 2 * lb - 1;
        double s = s_alpha[i1] + s_alpha[i1 + 1];
        double nlld = -(log(s) + (double)E * LN2D);
        float nll = (float)nlld;
        if (!(nll < 1e8f)) nll = 0.f;   // zero_infinity (covers inf/nan)
        nll_out[b] = nll;
    }
#undef STEPX
#undef STEP4
#undef LOADQ
#undef RENORM
}

// Kernel 3: deterministic reduction of 32 per-sample NLLs -> loss.
__global__ __launch_bounds__(64) void k_finalize(
    const float* __restrict__ nll, float* __restrict__ out)
{
    int tid = threadIdx.x;
    float v = (tid < B_DIM) ? nll[tid] : 0.f;
#pragma unroll
    for (int off = 32; off; off >>= 1) v += __shfl_down(v, off, 64);
    if (tid == 0) out[0] = v / (float)B_DIM;
}

extern "C" void kernel_launch(void* const* d_in, const int* in_sizes, int n_in,
                              void* d_out, int out_size, void* d_ws, size_t ws_size,
                              hipStream_t stream) {
    const float* hs      = (const float*)d_in[0];
    const float* W       = (const float*)d_in[1];
    const float* bias    = (const float*)d_in[2];
    const int*   hlens   = (const int*)d_in[3];
    const int*   ys_pad  = (const int*)d_in[4];
    const int*   ys_lens = (const int*)d_in[5];

    float* out   = (float*)d_out;
    float* logp  = out + 1;                                      // (B,T,V) log-softmax
    float* probs = out + 1 + (size_t)B_DIM * T_DIM * V_DIM;      // (B,T,V) softmax
    float* nll   = (float*)d_ws;                                 // 32 floats

    hipLaunchKernelGGL(k_logits_softmax, dim3(B_DIM * T_DIM / 256), dim3(256), 0, stream,
                       hs, W, bias, logp, probs);
    hipLaunchKernelGGL(k_ctc, dim3(B_DIM), dim3(64), 0, stream,
                       probs, ys_pad, hlens, ys_lens, nll);
    hipLaunchKernelGGL(k_finalize, dim3(1), dim3(64), 0, stream, nll, out);
}

// Round 6
// 235.541 us; speedup vs baseline: 1.0630x; 1.0630x over previous
//
#include <hip/hip_runtime.h>
#include <math.h>

#define B_DIM 32
#define T_DIM 2048
#define D_DIM 512
#define V_DIM 5
#define L_DIM 256
#define LN2D 0.6931471805599453

typedef const float __attribute__((address_space(1)))* gas_fp;
typedef float __attribute__((address_space(3)))* las_fp;

// Kernel 1: logits = hs @ W + b, log_softmax over V, probs. Thread-per-row.
__global__ __launch_bounds__(256) void k_logits_softmax(
    const float* __restrict__ hs, const float* __restrict__ W,
    const float* __restrict__ bias, float* __restrict__ logp,
    float* __restrict__ probs)
{
    int r = blockIdx.x * blockDim.x + threadIdx.x;   // row in [0, B*T)
    const float* x = hs + (size_t)r * D_DIM;

    float acc[V_DIM];
#pragma unroll
    for (int v = 0; v < V_DIM; ++v) acc[v] = bias[v];

    for (int k = 0; k < D_DIM; k += 8) {
        float4 xa = *reinterpret_cast<const float4*>(x + k);
        float4 xb = *reinterpret_cast<const float4*>(x + k + 4);
        const float xs[8] = {xa.x, xa.y, xa.z, xa.w, xb.x, xb.y, xb.z, xb.w};
#pragma unroll
        for (int j = 0; j < 8; ++j) {
#pragma unroll
            for (int v = 0; v < V_DIM; ++v)
                acc[v] = fmaf(xs[j], W[(k + j) * V_DIM + v], acc[v]);
        }
    }

    float m = fmaxf(fmaxf(fmaxf(acc[0], acc[1]), fmaxf(acc[2], acc[3])), acc[4]);
    float e[V_DIM];
    float s = 0.f;
#pragma unroll
    for (int v = 0; v < V_DIM; ++v) { e[v] = __expf(acc[v] - m); s += e[v]; }
    float lse = m + __logf(s);
    float inv = 1.f / s;

    size_t base = (size_t)r * V_DIM;
#pragma unroll
    for (int v = 0; v < V_DIM; ++v) {
        logp[base + v]  = acc[v] - lse;
        probs[base + v] = e[v] * inv;
    }
}

// Kernel 2: CTC forward scan. Linear-prob f64, single global frame, exact
// pow2 renorm every 16 steps (round-3/5-proven numerics). Round-6 changes:
// (a) probs converted once to f64 in LDS -> hot loop is ds_read_b64, no
//     per-step v_cvt_f64_f32 (saves ~20 cy/step of issue);
// (b) software-pipelined shuffle: N[7] computed FIRST each step and its
//     shfl_up issued immediately for the NEXT step; the raw result is
//     lane-0-masked at the consumption site one step later, so the
//     ds_bpermute latency hides under ~15 f64 ops.
__global__ __launch_bounds__(64) void k_ctc(
    const float* __restrict__ probs, const int* __restrict__ ys_pad,
    const int* __restrict__ hlens, const int* __restrict__ ys_lens,
    float* __restrict__ nll_out)
{
    __shared__ float  s_probs[(T_DIM + 8) * V_DIM];    // f32 staging
    __shared__ double s_probs64[(T_DIM + 8) * V_DIM];  // f64 hot copy
    __shared__ double s_alpha[513];

    const int b    = blockIdx.x;
    const int lane = threadIdx.x;        // 0..63
    const int hlen = hlens[b];
    const int lb   = ys_lens[b];
    const int Sb   = 2 * lb + 1;
    const float* pb = probs + (size_t)b * T_DIM * V_DIM;
    const int*  yrow = ys_pad + b * L_DIM;

    // ---- stage all T*V probs into LDS (f32), then convert to f64 ----
    for (int i = 0; i < (T_DIM * V_DIM) / 64; ++i) {
        __builtin_amdgcn_global_load_lds((gas_fp)(pb + i * 64 + lane),
                                         (las_fp)(&s_probs[i * 64]), 4, 0, 0);
    }
    asm volatile("s_waitcnt vmcnt(0)" ::: "memory");
    // single wave: LDS ops are in-order per wave, no barrier needed
#pragma unroll 8
    for (int i = 0; i < (T_DIM * V_DIM) / 64; ++i)
        s_probs64[i * 64 + lane] = (double)s_probs[i * 64 + lane];

    // labels for this lane's 4 odd states (8l+{1,3,5,7} -> labels 4l..4l+3)
    const int y0 = yrow[4 * lane + 0];
    const int y1 = yrow[4 * lane + 1];
    const int y2 = yrow[4 * lane + 2];
    const int y3 = yrow[4 * lane + 3];
    const int ym1 = (lane > 0) ? yrow[4 * lane - 1] : -1;

    // skip flags as 0/1 doubles (labels never blank per setup)
    const double sk0 = ((lane > 0) && (y0 != ym1)) ? 1.0 : 0.0;
    const double sk1 = (y1 != y0) ? 1.0 : 0.0;
    const double sk2 = (y2 != y1) ? 1.0 : 0.0;
    const double sk3 = (y3 != y2) ? 1.0 : 0.0;

    // valid-state masks; invalid states zeroed at every renorm
    bool vmask[9];
#pragma unroll
    for (int i = 0; i < 9; ++i) vmask[i] = (8 * lane + i) < Sb;

    double aA[9], aB[9];
#pragma unroll
    for (int i = 0; i < 9; ++i) aA[i] = 0.0;
    if (lane == 0) {
        aA[0] = s_probs64[0];            // state 0: blank at t=0
        aA[1] = s_probs64[y0];           // state 1: first label at t=0
    }
    int E = 0;   // global (wave-uniform) base-2 exponent, exact

    // carried raw shuffle of state 8l+7 (lane-0 masking at consumption)
    double p7r = __shfl_up(aA[7], 1, 64);

    // per-lane LDS read pointers (f64), advanced +20 doubles per 4-step block
    const double* p_bl = s_probs64 + V_DIM;          // blank col, row t=1
    const double* p_y0 = s_probs64 + V_DIM + y0;
    const double* p_y1 = s_probs64 + V_DIM + y1;
    const double* p_y2 = s_probs64 + V_DIM + y2;
    const double* p_y3 = s_probs64 + V_DIM + y3;

#define LOADQ(dst)                                                        \
    {                                                                     \
        _Pragma("unroll")                                                 \
        for (int s_ = 0; s_ < 4; ++s_) {                                  \
            dst[s_ * 5 + 0] = p_bl[s_ * 5];                               \
            dst[s_ * 5 + 1] = p_y0[s_ * 5];                               \
            dst[s_ * 5 + 2] = p_y1[s_ * 5];                               \
            dst[s_ * 5 + 3] = p_y2[s_ * 5];                               \
            dst[s_ * 5 + 4] = p_y3[s_ * 5];                               \
        }                                                                 \
        p_bl += 20; p_y0 += 20; p_y1 += 20; p_y2 += 20; p_y3 += 20;       \
    }

// N[7] first; its shuffle issued immediately for the next step; previous
// step's raw shuffle consumed here with lane-0 masking.
#define STEPX(O, N, L, s_)                                                \
    {                                                                     \
        N[7] = fma(sk3, O[5], O[7] + O[6]) * L[(s_) * 5 + 4];             \
        double p7 = (lane == 0) ? 0.0 : p7r;                              \
        p7r = __shfl_up(N[7], 1, 64);                                     \
        const double bl_ = L[(s_) * 5 + 0];                               \
        N[0] = (O[0] + p7) * bl_;                                         \
        N[1] = fma(sk0, p7,   O[1] + O[0]) * L[(s_) * 5 + 1];             \
        N[2] = (O[2] + O[1]) * bl_;                                       \
        N[3] = fma(sk1, O[1], O[3] + O[2]) * L[(s_) * 5 + 2];             \
        N[4] = (O[4] + O[3]) * bl_;                                       \
        N[5] = fma(sk2, O[3], O[5] + O[4]) * L[(s_) * 5 + 3];             \
        N[6] = (O[6] + O[5]) * bl_;                                       \
        N[8] = (O[8] + O[7]) * bl_;                                       \
    }

#define STEP4(L)                                                          \
    STEPX(aA, aB, L, 0); STEPX(aB, aA, L, 1);                             \
    STEPX(aA, aB, L, 2); STEPX(aB, aA, L, 3);

// Global renorm (wave-uniform E): exact pow2; also rescales carried p7r.
#define RENORM()                                                          \
    {                                                                     \
        double m_ = 0.0;                                                  \
        _Pragma("unroll")                                                 \
        for (int i_ = 0; i_ < 9; ++i_)                                    \
            m_ = fmax(m_, vmask[i_] ? aA[i_] : 0.0);                      \
        m_ = fmax(m_, __shfl_xor(m_, 1, 64));                             \
        m_ = fmax(m_, __shfl_xor(m_, 2, 64));                             \
        m_ = fmax(m_, __shfl_xor(m_, 4, 64));                             \
        m_ = fmax(m_, __shfl_xor(m_, 8, 64));                             \
        m_ = fmax(m_, __shfl_xor(m_, 16, 64));                            \
        m_ = fmax(m_, __shfl_xor(m_, 32, 64));                            \
        int e_ = 0;                                                       \
        (void)frexp(m_, &e_);            /* e_=0 when m_=0 */             \
        double sc_ = ldexp(1.0, -e_);                                     \
        _Pragma("unroll")                                                 \
        for (int i_ = 0; i_ < 9; ++i_)                                    \
            aA[i_] = vmask[i_] ? aA[i_] * sc_ : 0.0;                      \
        p7r *= sc_;                                                       \
        E += e_;                                                          \
    }

    const int NS = hlen - 1;       // steps t = 1..NS
    const int nfull = NS >> 2;     // full 4-step blocks
    double lpA[20], lpB[20];
    LOADQ(lpA);                    // rows 1..4

    int blk = 0;
    for (; blk + 2 <= nfull; blk += 2) {
        LOADQ(lpB);                // prefetch next block
        STEP4(lpA);
        LOADQ(lpA);                // prefetch block after
        STEP4(lpB);
        if (blk & 2) RENORM();     // every 16 steps (f64 headroom ample)
    }
    if (blk < nfull) {             // one leftover full block, data in lpA
        STEP4(lpA);
    }
    // tail steps (0..3): t = 4*nfull+1 .. NS
    for (int tt = 4 * nfull + 1; tt <= NS; ++tt) {
        const double* r_ = s_probs64 + tt * V_DIM;
        double lt[5] = { r_[0], r_[y0], r_[y1], r_[y2], r_[y3] };
        STEPX(aA, aB, lt, 0);
#pragma unroll
        for (int i = 0; i < 9; ++i) aA[i] = aB[i];
    }

    // ---- readout (single global frame: plain add) ----
#pragma unroll
    for (int i = 0; i < 8; ++i) s_alpha[8 * lane + i] = aA[i];
    if (lane == 63) s_alpha[512] = aA[8];
    __syncthreads();
    if (lane == 0) {
        int i1 = 2 * lb - 1;
        double s = s_alpha[i1] + s_alpha[i1 + 1];
        double nlld = -(log(s) + (double)E * LN2D);
        float nll = (float)nlld;
        if (!(nll < 1e8f)) nll = 0.f;   // zero_infinity (covers inf/nan)
        nll_out[b] = nll;
    }
#undef STEPX
#undef STEP4
#undef LOADQ
#undef RENORM
}

// Kernel 3: deterministic reduction of 32 per-sample NLLs -> loss.
__global__ __launch_bounds__(64) void k_finalize(
    const float* __restrict__ nll, float* __restrict__ out)
{
    int tid = threadIdx.x;
    float v = (tid < B_DIM) ? nll[tid] : 0.f;
#pragma unroll
    for (int off = 32; off; off >>= 1) v += __shfl_down(v, off, 64);
    if (tid == 0) out[0] = v / (float)B_DIM;
}

extern "C" void kernel_launch(void* const* d_in, const int* in_sizes, int n_in,
                              void* d_out, int out_size, void* d_ws, size_t ws_size,
                              hipStream_t stream) {
    const float* hs      = (const float*)d_in[0];
    const float* W       = (const float*)d_in[1];
    const float* bias    = (const float*)d_in[2];
    const int*   hlens   = (const int*)d_in[3];
    const int*   ys_pad  = (const int*)d_in[4];
    const int*   ys_lens = (const int*)d_in[5];

    float* out   = (float*)d_out;
    float* logp  = out + 1;                                      // (B,T,V) log-softmax
    float* probs = out + 1 + (size_t)B_DIM * T_DIM * V_DIM;      // (B,T,V) softmax
    float* nll   = (float*)d_ws;                                 // 32 floats

    hipLaunchKernelGGL(k_logits_softmax, dim3(B_DIM * T_DIM / 256), dim3(256), 0, stream,
                       hs, W, bias, logp, probs);
    hipLaunchKernelGGL(k_ctc, dim3(B_DIM), dim3(64), 0, stream,
                       probs, ys_pad, hlens, ys_lens, nll);
    hipLaunchKernelGGL(k_finalize, dim3(1), dim3(64), 0, stream, nll, out);
}

// Round 7
// 234.845 us; speedup vs baseline: 1.0661x; 1.0030x over previous
//
#include <hip/hip_runtime.h>
#include <math.h>

#define B_DIM 32
#define T_DIM 2048
#define D_DIM 512
#define V_DIM 5
#define L_DIM 256
#define LN2D 0.6931471805599453

typedef const float __attribute__((address_space(1)))* gas_fp;
typedef float __attribute__((address_space(3)))* las_fp;

// Kernel 1: logits = hs @ W + b, log_softmax over V, probs. Thread-per-row.
__global__ __launch_bounds__(256) void k_logits_softmax(
    const float* __restrict__ hs, const float* __restrict__ W,
    const float* __restrict__ bias, float* __restrict__ logp,
    float* __restrict__ probs)
{
    int r = blockIdx.x * blockDim.x + threadIdx.x;   // row in [0, B*T)
    const float* x = hs + (size_t)r * D_DIM;

    float acc[V_DIM];
#pragma unroll
    for (int v = 0; v < V_DIM; ++v) acc[v] = bias[v];

    for (int k = 0; k < D_DIM; k += 8) {
        float4 xa = *reinterpret_cast<const float4*>(x + k);
        float4 xb = *reinterpret_cast<const float4*>(x + k + 4);
        const float xs[8] = {xa.x, xa.y, xa.z, xa.w, xb.x, xb.y, xb.z, xb.w};
#pragma unroll
        for (int j = 0; j < 8; ++j) {
#pragma unroll
            for (int v = 0; v < V_DIM; ++v)
                acc[v] = fmaf(xs[j], W[(k + j) * V_DIM + v], acc[v]);
        }
    }

    float m = fmaxf(fmaxf(fmaxf(acc[0], acc[1]), fmaxf(acc[2], acc[3])), acc[4]);
    float e[V_DIM];
    float s = 0.f;
#pragma unroll
    for (int v = 0; v < V_DIM; ++v) { e[v] = __expf(acc[v] - m); s += e[v]; }
    float lse = m + __logf(s);
    float inv = 1.f / s;

    size_t base = (size_t)r * V_DIM;
#pragma unroll
    for (int v = 0; v < V_DIM; ++v) {
        logp[base + v]  = acc[v] - lse;
        probs[base + v] = e[v] * inv;
    }
}

// Kernel 2: CTC forward scan. Linear-prob f64, single global frame, exact
// pow2 renorm every 16 steps (round-3/5/6-proven numerics). Round-7:
// (a) probs transposed in LDS to [V][T] f64 -> LOADQ = 10 ds_read_b128 per
//     4-step block; worst lgkmcnt wait is now precise (<=12 DS ops after a
//     bpermute; r6 had 20+ which saturated lgkmcnt(15) and, with in-order
//     LDS completion, forced waiting on freshly-issued ~120cy reads);
// (b) p7r consumed at the END of each step (N7 -> shuffle issue -> N2..N8
//     -> consume -> N0,N1): ~128 cy of cover for the ~120 cy bpermute;
// (c) RENORM exact-max via LDS exponent gather (write int exponent, 16
//     broadcast b128 reads + int max tree) instead of the 6-deep dependent
//     f64 shuffle butterfly (~250 cy vs ~700+).
__global__ __launch_bounds__(64) void k_ctc(
    const float* __restrict__ probs, const int* __restrict__ ys_pad,
    const int* __restrict__ hlens, const int* __restrict__ ys_lens,
    float* __restrict__ nll_out)
{
    __shared__ float  s_probs[T_DIM * V_DIM];                    // f32 staging
    __shared__ __align__(16) double s_pT[V_DIM][T_DIM + 4];     // f64 [V][T] transposed
    __shared__ double s_alpha[513];
    __shared__ __align__(16) int s_expo[64];

    const int b    = blockIdx.x;
    const int lane = threadIdx.x;        // 0..63
    const int hlen = hlens[b];
    const int lb   = ys_lens[b];
    const int Sb   = 2 * lb + 1;
    const float* pb = probs + (size_t)b * T_DIM * V_DIM;
    const int*  yrow = ys_pad + b * L_DIM;

    // ---- stage all T*V probs into LDS (f32) ----
    for (int i = 0; i < (T_DIM * V_DIM) / 64; ++i) {
        __builtin_amdgcn_global_load_lds((gas_fp)(pb + i * 64 + lane),
                                         (las_fp)(&s_probs[i * 64]), 4, 0, 0);
    }
    asm volatile("s_waitcnt vmcnt(0)" ::: "memory");

    // ---- transpose + widen to f64: s_pT[v][t+3] (idx 4+4m is 16B-aligned,
    //      matching 4-step blocks starting at t=1) ----
    // single wave: per-wave in-order LDS, no barrier needed
    for (int i = 0; i < T_DIM / 64; ++i) {
        int t = i * 64 + lane;
        const float* sp = &s_probs[t * 5];
        s_pT[0][t + 3] = (double)sp[0];
        s_pT[1][t + 3] = (double)sp[1];
        s_pT[2][t + 3] = (double)sp[2];
        s_pT[3][t + 3] = (double)sp[3];
        s_pT[4][t + 3] = (double)sp[4];
    }

    // labels for this lane's 4 odd states (8l+{1,3,5,7} -> labels 4l..4l+3)
    const int y0 = yrow[4 * lane + 0];
    const int y1 = yrow[4 * lane + 1];
    const int y2 = yrow[4 * lane + 2];
    const int y3 = yrow[4 * lane + 3];
    const int ym1 = (lane > 0) ? yrow[4 * lane - 1] : -1;

    // skip flags as 0/1 doubles (labels never blank per setup)
    const double sk0 = ((lane > 0) && (y0 != ym1)) ? 1.0 : 0.0;
    const double sk1 = (y1 != y0) ? 1.0 : 0.0;
    const double sk2 = (y2 != y1) ? 1.0 : 0.0;
    const double sk3 = (y3 != y2) ? 1.0 : 0.0;

    // valid-state masks; invalid states zeroed at every renorm
    bool vmask[9];
#pragma unroll
    for (int i = 0; i < 9; ++i) vmask[i] = (8 * lane + i) < Sb;

    double aA[9], aB[9];
#pragma unroll
    for (int i = 0; i < 9; ++i) aA[i] = 0.0;
    if (lane == 0) {
        aA[0] = (double)s_probs[0];      // state 0: blank at t=0
        aA[1] = (double)s_probs[y0];     // state 1: first label at t=0
    }
    int E = 0;   // global (wave-uniform) base-2 exponent, exact

    // carried raw shuffle of state 8l+7 (lane-0 masking at consumption)
    double p7r = __shfl_up(aA[7], 1, 64);

    // per-lane LDS row pointers (f64, transposed), +4 doubles per block
    const double* q_bl = &s_pT[0][4];
    const double* q_y0 = &s_pT[y0][4];
    const double* q_y1 = &s_pT[y1][4];
    const double* q_y2 = &s_pT[y2][4];
    const double* q_y3 = &s_pT[y3][4];

// dst layout: dst[c*4 + s_], c: 0=blank, 1..4 = y0..y3; s_ = step in block
#define LOADROW(dst, off, q)                                              \
    {                                                                     \
        double2 v0_ = *(const double2*)(q);                               \
        double2 v1_ = *(const double2*)((q) + 2);                         \
        dst[(off) + 0] = v0_.x; dst[(off) + 1] = v0_.y;                   \
        dst[(off) + 2] = v1_.x; dst[(off) + 3] = v1_.y;                   \
        (q) += 4;                                                         \
    }
#define LOADQ(dst)                                                        \
    {                                                                     \
        LOADROW(dst, 0,  q_bl); LOADROW(dst, 4,  q_y0);                   \
        LOADROW(dst, 8,  q_y1); LOADROW(dst, 12, q_y2);                   \
        LOADROW(dst, 16, q_y3);                                           \
    }

// N[7] first; its shuffle issued immediately for the next step; previous
// step's raw shuffle consumed LAST (max cover for bpermute latency).
#define STEPX(O, N, L, s_)                                                \
    {                                                                     \
        N[7] = fma(sk3, O[5], O[7] + O[6]) * L[16 + (s_)];                \
        double np7_ = __shfl_up(N[7], 1, 64);                             \
        const double bl_ = L[0 + (s_)];                                   \
        N[2] = (O[2] + O[1]) * bl_;                                       \
        N[3] = fma(sk1, O[1], O[3] + O[2]) * L[8 + (s_)];                 \
        N[4] = (O[4] + O[3]) * bl_;                                       \
        N[5] = fma(sk2, O[3], O[5] + O[4]) * L[12 + (s_)];                \
        N[6] = (O[6] + O[5]) * bl_;                                       \
        N[8] = (O[8] + O[7]) * bl_;                                       \
        double p7_ = (lane == 0) ? 0.0 : p7r;                             \
        N[0] = (O[0] + p7_) * bl_;                                        \
        N[1] = fma(sk0, p7_, O[1] + O[0]) * L[4 + (s_)];                  \
        p7r = np7_;                                                       \
    }

#define STEP4(L)                                                          \
    STEPX(aA, aB, L, 0); STEPX(aB, aA, L, 1);                             \
    STEPX(aA, aB, L, 2); STEPX(aB, aA, L, 3);

// Exact-max global renorm via LDS exponent gather: biased exponent is
// monotone in the positive double's value, so int-max of exponents gives
// the true max's exponent. Wave-uniform branch; rescales p7r too.
#define RENORM()                                                          \
    {                                                                     \
        double m_ = 0.0;                                                  \
        _Pragma("unroll")                                                 \
        for (int i_ = 0; i_ < 9; ++i_)                                    \
            m_ = fmax(m_, vmask[i_] ? aA[i_] : 0.0);                      \
        s_expo[lane] = (__double2hiint(m_) >> 20) & 0x7ff;                \
        int em_ = 0;                                                      \
        _Pragma("unroll")                                                 \
        for (int g_ = 0; g_ < 16; ++g_) {                                 \
            int4 e4_ = *(const int4*)&s_expo[g_ * 4];                     \
            em_ = max(em_, max(max(e4_.x, e4_.y), max(e4_.z, e4_.w)));    \
        }                                                                 \
        if (em_ > 0) {                                                    \
            double sc_ = __hiloint2double((2046 - em_) << 20, 0);         \
            _Pragma("unroll")                                             \
            for (int i_ = 0; i_ < 9; ++i_)                                \
                aA[i_] = vmask[i_] ? aA[i_] * sc_ : 0.0;                  \
            p7r *= sc_;                                                   \
            E += em_ - 1023;                                              \
        } else {                                                          \
            _Pragma("unroll")                                             \
            for (int i_ = 0; i_ < 9; ++i_)                                \
                if (!vmask[i_]) aA[i_] = 0.0;                             \
        }                                                                 \
    }

    const int NS = hlen - 1;       // steps t = 1..NS
    const int nfull = NS >> 2;     // full 4-step blocks
    double lpA[20], lpB[20];
    LOADQ(lpA);                    // block 0 (t=1..4)

    int blk = 0;
    for (; blk + 2 <= nfull; blk += 2) {
        LOADQ(lpB);                // prefetch next block
        STEP4(lpA);
        LOADQ(lpA);                // prefetch block after
        STEP4(lpB);
        if (blk & 2) RENORM();     // every 16 steps (f64 headroom ample)
    }
    if (blk < nfull) {             // one leftover full block, data in lpA
        STEP4(lpA);
    }
    // tail steps (0..3): t = 4*nfull+1 .. NS
    for (int tt = 4 * nfull + 1; tt <= NS; ++tt) {
        double lt[17];
        lt[0]  = s_pT[0][tt + 3];
        lt[4]  = s_pT[y0][tt + 3];
        lt[8]  = s_pT[y1][tt + 3];
        lt[12] = s_pT[y2][tt + 3];
        lt[16] = s_pT[y3][tt + 3];
        STEPX(aA, aB, lt, 0);
#pragma unroll
        for (int i = 0; i < 9; ++i) aA[i] = aB[i];
    }

    // ---- readout (single global frame: plain add) ----
#pragma unroll
    for (int i = 0; i < 8; ++i) s_alpha[8 * lane + i] = aA[i];
    if (lane == 63) s_alpha[512] = aA[8];
    __syncthreads();
    if (lane == 0) {
        int i1 = 2 * lb - 1;
        double s = s_alpha[i1] + s_alpha[i1 + 1];
        double nlld = -(log(s) + (double)E * LN2D);
        float nll = (float)nlld;
        if (!(nll < 1e8f)) nll = 0.f;   // zero_infinity (covers inf/nan)
        nll_out[b] = nll;
    }
#undef STEPX
#undef STEP4
#undef LOADQ
#undef LOADROW
#undef RENORM
}

// Kernel 3: deterministic reduction of 32 per-sample NLLs -> loss.
__global__ __launch_bounds__(64) void k_finalize(
    const float* __restrict__ nll, float* __restrict__ out)
{
    int tid = threadIdx.x;
    float v = (tid < B_DIM) ? nll[tid] : 0.f;
#pragma unroll
    for (int off = 32; off; off >>= 1) v += __shfl_down(v, off, 64);
    if (tid == 0) out[0] = v / (float)B_DIM;
}

extern "C" void kernel_launch(void* const* d_in, const int* in_sizes, int n_in,
                              void* d_out, int out_size, void* d_ws, size_t ws_size,
                              hipStream_t stream) {
    const float* hs      = (const float*)d_in[0];
    const float* W       = (const float*)d_in[1];
    const float* bias    = (const float*)d_in[2];
    const int*   hlens   = (const int*)d_in[3];
    const int*   ys_pad  = (const int*)d_in[4];
    const int*   ys_lens = (const int*)d_in[5];

    float* out   = (float*)d_out;
    float* logp  = out + 1;                                      // (B,T,V) log-softmax
    float* probs = out + 1 + (size_t)B_DIM * T_DIM * V_DIM;      // (B,T,V) softmax
    float* nll   = (float*)d_ws;                                 // 32 floats

    hipLaunchKernelGGL(k_logits_softmax, dim3(B_DIM * T_DIM / 256), dim3(256), 0, stream,
                       hs, W, bias, logp, probs);
    hipLaunchKernelGGL(k_ctc, dim3(B_DIM), dim3(64), 0, stream,
                       probs, ys_pad, hlens, ys_lens, nll);
    hipLaunchKernelGGL(k_finalize, dim3(1), dim3(64), 0, stream, nll, out);
}

// Round 8
// 187.468 us; speedup vs baseline: 1.3355x; 1.2527x over previous
//
#include <hip/hip_runtime.h>
#include <math.h>

#define B_DIM 32
#define T_DIM 2048
#define D_DIM 512
#define V_DIM 5
#define L_DIM 256
#define LN2D 0.6931471805599453

typedef const float __attribute__((address_space(1)))* gas_fp;
typedef float __attribute__((address_space(3)))* las_fp;

// ---- DPP helpers (gfx9-family VALU cross-lane, no DS pipe) ----
// wave_shr:1 = 0x138; row_shr:n = 0x110+n; row_bcast15 = 0x142; bcast31 = 0x143
__device__ __forceinline__ double dpp_shr1_f64(double x) {
    int lo = __double2loint(x), hi = __double2hiint(x);
    int slo = __builtin_amdgcn_update_dpp(0, lo, 0x138, 0xf, 0xf, true);
    int shi = __builtin_amdgcn_update_dpp(0, hi, 0x138, 0xf, 0xf, true);
    return __hiloint2double(shi, slo);   // lane 0 -> +0.0 via bound_ctrl
}
__device__ __forceinline__ int wave_imax_dpp(int e) {
    e = max(e, __builtin_amdgcn_update_dpp(0, e, 0x111, 0xf, 0xf, true));
    e = max(e, __builtin_amdgcn_update_dpp(0, e, 0x112, 0xf, 0xf, true));
    e = max(e, __builtin_amdgcn_update_dpp(0, e, 0x114, 0xf, 0xf, true));
    e = max(e, __builtin_amdgcn_update_dpp(0, e, 0x118, 0xf, 0xf, true));
    e = max(e, __builtin_amdgcn_update_dpp(0, e, 0x142, 0xf, 0xf, true));
    e = max(e, __builtin_amdgcn_update_dpp(0, e, 0x143, 0xf, 0xf, true));
    return __builtin_amdgcn_readlane(e, 63);   // wave-uniform (SGPR)
}

// Kernel 1: logits = hs @ W + b, log_softmax over V, probs. Thread-per-row.
__global__ __launch_bounds__(256) void k_logits_softmax(
    const float* __restrict__ hs, const float* __restrict__ W,
    const float* __restrict__ bias, float* __restrict__ logp,
    float* __restrict__ probs)
{
    int r = blockIdx.x * blockDim.x + threadIdx.x;   // row in [0, B*T)
    const float* x = hs + (size_t)r * D_DIM;

    float acc[V_DIM];
#pragma unroll
    for (int v = 0; v < V_DIM; ++v) acc[v] = bias[v];

    for (int k = 0; k < D_DIM; k += 8) {
        float4 xa = *reinterpret_cast<const float4*>(x + k);
        float4 xb = *reinterpret_cast<const float4*>(x + k + 4);
        const float xs[8] = {xa.x, xa.y, xa.z, xa.w, xb.x, xb.y, xb.z, xb.w};
#pragma unroll
        for (int j = 0; j < 8; ++j) {
#pragma unroll
            for (int v = 0; v < V_DIM; ++v)
                acc[v] = fmaf(xs[j], W[(k + j) * V_DIM + v], acc[v]);
        }
    }

    float m = fmaxf(fmaxf(fmaxf(acc[0], acc[1]), fmaxf(acc[2], acc[3])), acc[4]);
    float e[V_DIM];
    float s = 0.f;
#pragma unroll
    for (int v = 0; v < V_DIM; ++v) { e[v] = __expf(acc[v] - m); s += e[v]; }
    float lse = m + __logf(s);
    float inv = 1.f / s;

    size_t base = (size_t)r * V_DIM;
#pragma unroll
    for (int v = 0; v < V_DIM; ++v) {
        logp[base + v]  = acc[v] - lse;
        probs[base + v] = e[v] * inv;
    }
}

// Kernel 2: CTC forward scan. Linear-prob f64, single global frame, exact
// pow2 renorm every 16 steps (r3/5/6/7-proven numerics). Round-8 change:
// the per-step cross-lane shuffle is a DPP wave_shr:1 (pure VALU, ~4cy,
// bound_ctrl zero-fills lane 0) instead of 2x ds_bpermute (~120cy LDS
// round-trip on the dependency path every step -- r4-r7 all plateaued at
// 220-240 cy/step regardless of f32/f64 because of it). RENORM's max is a
// DPP int-exponent reduction (row_shr chain + bcast15/31 + readlane 63),
// also DS-free. Remaining DS: 10 prefetched ds_read_b128 per 4-step block,
// consumed a block later (fully covered).
__global__ __launch_bounds__(64) void k_ctc(
    const float* __restrict__ probs, const int* __restrict__ ys_pad,
    const int* __restrict__ hlens, const int* __restrict__ ys_lens,
    float* __restrict__ nll_out)
{
    __shared__ float  s_probs[T_DIM * V_DIM];                    // f32 staging
    __shared__ __align__(16) double s_pT[V_DIM][T_DIM + 4];     // f64 [V][T] transposed
    __shared__ double s_alpha[513];

    const int b    = blockIdx.x;
    const int lane = threadIdx.x;        // 0..63
    const int hlen = hlens[b];
    const int lb   = ys_lens[b];
    const int Sb   = 2 * lb + 1;
    const float* pb = probs + (size_t)b * T_DIM * V_DIM;
    const int*  yrow = ys_pad + b * L_DIM;

    // ---- stage all T*V probs into LDS (f32) ----
    for (int i = 0; i < (T_DIM * V_DIM) / 64; ++i) {
        __builtin_amdgcn_global_load_lds((gas_fp)(pb + i * 64 + lane),
                                         (las_fp)(&s_probs[i * 64]), 4, 0, 0);
    }
    asm volatile("s_waitcnt vmcnt(0)" ::: "memory");

    // ---- transpose + widen to f64: s_pT[v][t+3] (idx 4+4m is 16B-aligned,
    //      matching 4-step blocks starting at t=1) ----
    // single wave: per-wave in-order LDS, no barrier needed
    for (int i = 0; i < T_DIM / 64; ++i) {
        int t = i * 64 + lane;
        const float* sp = &s_probs[t * 5];
        s_pT[0][t + 3] = (double)sp[0];
        s_pT[1][t + 3] = (double)sp[1];
        s_pT[2][t + 3] = (double)sp[2];
        s_pT[3][t + 3] = (double)sp[3];
        s_pT[4][t + 3] = (double)sp[4];
    }

    // labels for this lane's 4 odd states (8l+{1,3,5,7} -> labels 4l..4l+3)
    const int y0 = yrow[4 * lane + 0];
    const int y1 = yrow[4 * lane + 1];
    const int y2 = yrow[4 * lane + 2];
    const int y3 = yrow[4 * lane + 3];
    const int ym1 = (lane > 0) ? yrow[4 * lane - 1] : -1;

    // skip flags as 0/1 doubles (labels never blank per setup)
    const double sk0 = ((lane > 0) && (y0 != ym1)) ? 1.0 : 0.0;
    const double sk1 = (y1 != y0) ? 1.0 : 0.0;
    const double sk2 = (y2 != y1) ? 1.0 : 0.0;
    const double sk3 = (y3 != y2) ? 1.0 : 0.0;

    // valid-state masks; invalid states zeroed at every renorm
    bool vmask[9];
#pragma unroll
    for (int i = 0; i < 9; ++i) vmask[i] = (8 * lane + i) < Sb;

    double aA[9], aB[9];
#pragma unroll
    for (int i = 0; i < 9; ++i) aA[i] = 0.0;
    if (lane == 0) {
        aA[0] = (double)s_probs[0];      // state 0: blank at t=0
        aA[1] = (double)s_probs[y0];     // state 1: first label at t=0
    }
    int E = 0;   // global (wave-uniform) base-2 exponent, exact

    // per-lane LDS row pointers (f64, transposed), +4 doubles per block
    const double* q_bl = &s_pT[0][4];
    const double* q_y0 = &s_pT[y0][4];
    const double* q_y1 = &s_pT[y1][4];
    const double* q_y2 = &s_pT[y2][4];
    const double* q_y3 = &s_pT[y3][4];

// dst layout: dst[c*4 + s_], c: 0=blank, 1..4 = y0..y3; s_ = step in block
#define LOADROW(dst, off, q)                                              \
    {                                                                     \
        double2 v0_ = *(const double2*)(q);                               \
        double2 v1_ = *(const double2*)((q) + 2);                         \
        dst[(off) + 0] = v0_.x; dst[(off) + 1] = v0_.y;                   \
        dst[(off) + 2] = v1_.x; dst[(off) + 3] = v1_.y;                   \
        (q) += 4;                                                         \
    }
#define LOADQ(dst)                                                        \
    {                                                                     \
        LOADROW(dst, 0,  q_bl); LOADROW(dst, 4,  q_y0);                   \
        LOADROW(dst, 8,  q_y1); LOADROW(dst, 12, q_y2);                   \
        LOADROW(dst, 16, q_y3);                                           \
    }

// DPP shuffle of O[7] at step start (VALU, lane0 auto-zero); N2..N8 give
// ~6 instructions of cover for the dpp->use latency before N0/N1 consume.
#define STEPX(O, N, L, s_)                                                \
    {                                                                     \
        double p7_ = dpp_shr1_f64(O[7]);                                  \
        const double bl_ = L[0 + (s_)];                                   \
        N[7] = fma(sk3, O[5], O[7] + O[6]) * L[16 + (s_)];                \
        N[2] = (O[2] + O[1]) * bl_;                                       \
        N[3] = fma(sk1, O[1], O[3] + O[2]) * L[8 + (s_)];                 \
        N[4] = (O[4] + O[3]) * bl_;                                       \
        N[5] = fma(sk2, O[3], O[5] + O[4]) * L[12 + (s_)];                \
        N[6] = (O[6] + O[5]) * bl_;                                       \
        N[8] = (O[8] + O[7]) * bl_;                                       \
        N[0] = (O[0] + p7_) * bl_;                                        \
        N[1] = fma(sk0, p7_, O[1] + O[0]) * L[4 + (s_)];                  \
    }

#define STEP4(L)                                                          \
    STEPX(aA, aB, L, 0); STEPX(aB, aA, L, 1);                             \
    STEPX(aA, aB, L, 2); STEPX(aB, aA, L, 3);

// Exact-max global renorm: biased exponent is monotone in the positive
// double's value, so wave-max of int exponents (DPP reduction) gives the
// true max's exponent. Wave-uniform branch; exact pow2 rescale.
#define RENORM()                                                          \
    {                                                                     \
        double m_ = 0.0;                                                  \
        _Pragma("unroll")                                                 \
        for (int i_ = 0; i_ < 9; ++i_)                                    \
            m_ = fmax(m_, vmask[i_] ? aA[i_] : 0.0);                      \
        int em_ = wave_imax_dpp((__double2hiint(m_) >> 20) & 0x7ff);      \
        if (em_ > 0) {                                                    \
            double sc_ = __hiloint2double((2046 - em_) << 20, 0);         \
            _Pragma("unroll")                                             \
            for (int i_ = 0; i_ < 9; ++i_)                                \
                aA[i_] = vmask[i_] ? aA[i_] * sc_ : 0.0;                  \
            E += em_ - 1023;                                              \
        } else {                                                          \
            _Pragma("unroll")                                             \
            for (int i_ = 0; i_ < 9; ++i_)                                \
                if (!vmask[i_]) aA[i_] = 0.0;                             \
        }                                                                 \
    }

    const int NS = hlen - 1;       // steps t = 1..NS
    const int nfull = NS >> 2;     // full 4-step blocks
    double lpA[20], lpB[20];
    LOADQ(lpA);                    // block 0 (t=1..4)

    int blk = 0;
    for (; blk + 2 <= nfull; blk += 2) {
        LOADQ(lpB);                // prefetch next block
        STEP4(lpA);
        LOADQ(lpA);                // prefetch block after
        STEP4(lpB);
        if (blk & 2) RENORM();     // every 16 steps (f64 headroom ample)
    }
    if (blk < nfull) {             // one leftover full block, data in lpA
        STEP4(lpA);
    }
    // tail steps (0..3): t = 4*nfull+1 .. NS
    for (int tt = 4 * nfull + 1; tt <= NS; ++tt) {
        double lt[17];
        lt[0]  = s_pT[0][tt + 3];
        lt[4]  = s_pT[y0][tt + 3];
        lt[8]  = s_pT[y1][tt + 3];
        lt[12] = s_pT[y2][tt + 3];
        lt[16] = s_pT[y3][tt + 3];
        STEPX(aA, aB, lt, 0);
#pragma unroll
        for (int i = 0; i < 9; ++i) aA[i] = aB[i];
    }

    // ---- readout (single global frame: plain add) ----
#pragma unroll
    for (int i = 0; i < 8; ++i) s_alpha[8 * lane + i] = aA[i];
    if (lane == 63) s_alpha[512] = aA[8];
    __syncthreads();
    if (lane == 0) {
        int i1 = 2 * lb - 1;
        double s = s_alpha[i1] + s_alpha[i1 + 1];
        double nlld = -(log(s) + (double)E * LN2D);
        float nll = (float)nlld;
        if (!(nll < 1e8f)) nll = 0.f;   // zero_infinity (covers inf/nan)
        nll_out[b] = nll;
    }
#undef STEPX
#undef STEP4
#undef LOADQ
#undef LOADROW
#undef RENORM
}

// Kernel 3: deterministic reduction of 32 per-sample NLLs -> loss.
__global__ __launch_bounds__(64) void k_finalize(
    const float* __restrict__ nll, float* __restrict__ out)
{
    int tid = threadIdx.x;
    float v = (tid < B_DIM) ? nll[tid] : 0.f;
#pragma unroll
    for (int off = 32; off; off >>= 1) v += __shfl_down(v, off, 64);
    if (tid == 0) out[0] = v / (float)B_DIM;
}

extern "C" void kernel_launch(void* const* d_in, const int* in_sizes, int n_in,
                              void* d_out, int out_size, void* d_ws, size_t ws_size,
                              hipStream_t stream) {
    const float* hs      = (const float*)d_in[0];
    const float* W       = (const float*)d_in[1];
    const float* bias    = (const float*)d_in[2];
    const int*   hlens   = (const int*)d_in[3];
    const int*   ys_pad  = (const int*)d_in[4];
    const int*   ys_lens = (const int*)d_in[5];

    float* out   = (float*)d_out;
    float* logp  = out + 1;                                      // (B,T,V) log-softmax
    float* probs = out + 1 + (size_t)B_DIM * T_DIM * V_DIM;      // (B,T,V) softmax
    float* nll   = (float*)d_ws;                                 // 32 floats

    hipLaunchKernelGGL(k_logits_softmax, dim3(B_DIM * T_DIM / 256), dim3(256), 0, stream,
                       hs, W, bias, logp, probs);
    hipLaunchKernelGGL(k_ctc, dim3(B_DIM), dim3(64), 0, stream,
                       probs, ys_pad, hlens, ys_lens, nll);
    hipLaunchKernelGGL(k_finalize, dim3(1), dim3(64), 0, stream, nll, out);
}